// Round 8
// baseline (49.338 us; speedup 1.0000x reference)
//
#include <hip/hip_runtime.h>
#include <stdint.h>

#define KSEL 10
#define NTHREADS 256
#define CAP 2560            // candidate slots; also exactly fits fallback dump 256*10
#define BUFSZ (CAP + 16)

using f32x4 = __attribute__((ext_vector_type(4))) float;

__device__ __forceinline__ unsigned long long ullmin(unsigned long long a, unsigned long long b) {
    return a < b ? a : b;
}

__global__ void __launch_bounds__(NTHREADS)
knn_topk_kernel(const float* __restrict__ ged, const float* __restrict__ y,
                const float* __restrict__ coef, float* __restrict__ out, int n_train)
{
    __shared__ unsigned long long sbuf[BUFSZ];
    __shared__ int cnt;

    const int tid = threadIdx.x;
    const int row = blockIdx.x;
    const float* __restrict__ x = ged + (size_t)row * (size_t)n_train;

    // vector path only if divisible (true here: 50000 % 4 == 0)
    const int n4 = ((n_train & 3) == 0) ? (n_train >> 2) : 0;
    const f32x4* __restrict__ x4 = (const f32x4*)x;

    int len = -1;
    float T = 2.0e-3f;

    for (int attempt = 0; attempt < 24; ++attempt) {
        if (tid == 0) cnt = 0;
        __syncthreads();

        for (int i = tid; i < n4; i += NTHREADS) {
            f32x4 v = __builtin_nontemporal_load(x4 + i);
            // one branch per 16B: min-prefilter (rarely true: ~0.8%)
            float m01 = fminf(v[0], v[1]);
            float m23 = fminf(v[2], v[3]);
            if (fminf(m01, m23) < T) {
                int base = i << 2;
                #pragma unroll
                for (int c = 0; c < 4; ++c) {
                    if (v[c] < T) {
                        int p = atomicAdd(&cnt, 1);
                        if (p < CAP)
                            sbuf[p] = ((unsigned long long)__float_as_uint(v[c]) << 32) | (unsigned)(base + c);
                    }
                }
            }
        }
        for (int i = (n4 << 2) + tid; i < n_train; i += NTHREADS) {
            float v = x[i];
            if (v < T) {
                int p = atomicAdd(&cnt, 1);
                if (p < CAP)
                    sbuf[p] = ((unsigned long long)__float_as_uint(v) << 32) | (unsigned)i;
            }
        }
        __syncthreads();

        int c = cnt;                         // uniform across block
        if (c >= KSEL && c <= CAP) { len = c; break; }
        T = (c < KSEL) ? T * 8.0f : T * 0.125f;
        __syncthreads();                     // protect cnt until everyone has read it
    }

    if (len < 0) {
        // Exact fallback (any data distribution): per-thread sorted top-K, then merge.
        unsigned long long loc[KSEL];
        #pragma unroll
        for (int j = 0; j < KSEL; ++j) loc[j] = ~0ull;
        for (int i = tid; i < n_train; i += NTHREADS) {
            unsigned long long key = ((unsigned long long)__float_as_uint(x[i]) << 32) | (unsigned)i;
            if (key < loc[KSEL - 1]) {
                loc[KSEL - 1] = key;
                #pragma unroll
                for (int j = KSEL - 1; j > 0; --j) {
                    if (loc[j] < loc[j - 1]) {
                        unsigned long long t = loc[j]; loc[j] = loc[j - 1]; loc[j - 1] = t;
                    }
                }
            }
        }
        __syncthreads();
        #pragma unroll
        for (int j = 0; j < KSEL; ++j) sbuf[tid * KSEL + j] = loc[j];
        __syncthreads();
        len = NTHREADS * KSEL;
    }

    // ---- wave-0-only, barrier-free extraction ----
    // Each sbuf slot j is owned by lane (j & 63): removal writes and next-round
    // reads of a slot always happen in the same lane -> no cross-lane hazard.
    if (tid >= 64) return;

    unsigned long long mykey = ~0ull;   // lane r ends up holding winner r (r < KSEL)

    #pragma unroll
    for (int r = 0; r < KSEL; ++r) {
        unsigned long long m = ~0ull;
        for (int j = tid; j < len; j += 64) m = ullmin(m, sbuf[j]);
        #pragma unroll
        for (int off = 32; off > 0; off >>= 1)
            m = ullmin(m, __shfl_xor((long long)m, off, 64));
        // all lanes now hold the round-r winner
        if (tid == r) mykey = m;
        for (int j = tid; j < len; j += 64) if (sbuf[j] == m) sbuf[j] = ~0ull;
    }

    // lanes 0..KSEL-1 gather y and compute exp weights in parallel
    float s = 0.0f, wy = 0.0f;
    if (tid < KSEL) {
        float cd = coef[0];
        float alpha = cd * cd;
        float v = __uint_as_float((unsigned)(mykey >> 32));
        int idx = (int)(unsigned)(mykey & 0xffffffffull);
        s  = expf(-alpha * v);
        wy = s * y[idx];
    }
    #pragma unroll
    for (int off = 32; off > 0; off >>= 1) {
        s  += __shfl_xor(s,  off, 64);
        wy += __shfl_xor(wy, off, 64);
    }
    if (tid == 0) out[row] = wy / s;
}

extern "C" void kernel_launch(void* const* d_in, const int* in_sizes, int n_in,
                              void* d_out, int out_size, void* d_ws, size_t ws_size,
                              hipStream_t stream) {
    const float* ged  = (const float*)d_in[0];
    const float* y    = (const float*)d_in[1];
    const float* coef = (const float*)d_in[2];
    float* out = (float*)d_out;

    const int rows    = out_size;              // = NB_TEST = 1024
    const int n_train = in_sizes[0] / rows;    // = 50000

    knn_topk_kernel<<<rows, NTHREADS, 0, stream>>>(ged, y, coef, out, n_train);
}